// Round 1
// baseline (1395.951 us; speedup 1.0000x reference)
//
#include <hip/hip_runtime.h>
#include <math.h>

#define NPTS 8192
#define DIMW 384
#define BM   16
#define LDH  388          // padded LDS row stride (>=385, mult of 4)
#define TE   192          // threads in embed kernel (each owns cols t, t+192)
#define DBLK 32           // rows per dist block
#define SCH  256          // chunk size
#define NCH  32           // chunks

// ---------------- block-wide deterministic sum (256 threads) ----------------
__device__ __forceinline__ float block_sum_256(float v, float* scratch, int t) {
#pragma unroll
  for (int o = 32; o > 0; o >>= 1) v += __shfl_xor(v, o, 64);
  __syncthreads();                       // protect scratch reuse across calls
  if ((t & 63) == 0) scratch[t >> 6] = v;
  __syncthreads();
  return scratch[0] + scratch[1] + scratch[2] + scratch[3];
}

// ---------------- one dense layer: hout = act(hin @ W), W row-major [K][384]
template <bool RELU>
__device__ __forceinline__ void layer(const float (*hin)[LDH], float (*hout)[LDH],
                                      const float* __restrict__ W, int K,
                                      int n0, int n1) {
  float acc0[BM], acc1[BM];
#pragma unroll
  for (int m = 0; m < BM; ++m) { acc0[m] = 0.f; acc1[m] = 0.f; }
  int k0 = 0;
  for (; k0 + 4 <= K; k0 += 4) {
    const float* Wk = W + (size_t)k0 * DIMW;
    float w00 = Wk[n0],            w10 = Wk[n1];
    float w01 = Wk[DIMW + n0],     w11 = Wk[DIMW + n1];
    float w02 = Wk[2 * DIMW + n0], w12 = Wk[2 * DIMW + n1];
    float w03 = Wk[3 * DIMW + n0], w13 = Wk[3 * DIMW + n1];
#pragma unroll
    for (int m = 0; m < BM; ++m) {
      const float4 h = *(const float4*)&hin[m][k0];
      float a0 = acc0[m], a1 = acc1[m];
      a0 = fmaf(h.x, w00, a0); a1 = fmaf(h.x, w10, a1);
      a0 = fmaf(h.y, w01, a0); a1 = fmaf(h.y, w11, a1);
      a0 = fmaf(h.z, w02, a0); a1 = fmaf(h.z, w12, a1);
      a0 = fmaf(h.w, w03, a0); a1 = fmaf(h.w, w13, a1);
      acc0[m] = a0; acc1[m] = a1;
    }
  }
  for (; k0 < K; ++k0) {                 // tail (K=385 input layer)
    float w0 = W[(size_t)k0 * DIMW + n0];
    float w1 = W[(size_t)k0 * DIMW + n1];
#pragma unroll
    for (int m = 0; m < BM; ++m) {
      float h = hin[m][k0];
      acc0[m] = fmaf(h, w0, acc0[m]);
      acc1[m] = fmaf(h, w1, acc1[m]);
    }
  }
#pragma unroll
  for (int m = 0; m < BM; ++m) {
    hout[m][n0] = RELU ? fmaxf(acc0[m], 0.f) : acc0[m];
    hout[m][n1] = RELU ? fmaxf(acc1[m], 0.f) : acc1[m];
  }
  __syncthreads();
}

// ---------------- normalize rows of h and write (or add) to global emb ------
template <bool ADD>
__device__ __forceinline__ void norm_write(const float (*h)[LDH],
                                           float* __restrict__ embp,
                                           float* invn, int t, int n0, int n1) {
  if (t < 64) {                          // wave 0: 4 lanes per point
    int p = t >> 2, q = t & 3;
    const float* row = &h[p][q * 96];
    float s = 0.f;
#pragma unroll
    for (int k = 0; k < 96; k += 4) {
      float4 x = *(const float4*)&row[k];
      s = fmaf(x.x, x.x, s); s = fmaf(x.y, x.y, s);
      s = fmaf(x.z, x.z, s); s = fmaf(x.w, x.w, s);
    }
    s += __shfl_xor(s, 1, 64);
    s += __shfl_xor(s, 2, 64);
    if (q == 0) invn[p] = 1.f / (sqrtf(s) + 1e-5f);
  }
  __syncthreads();
#pragma unroll
  for (int m = 0; m < BM; ++m) {
    float a0 = h[m][n0] * invn[m];
    float a1 = h[m][n1] * invn[m];
    size_t o0 = (size_t)m * DIMW + n0, o1 = (size_t)m * DIMW + n1;
    if (ADD) { embp[o0] += a0; embp[o1] += a1; }
    else     { embp[o0] = a0;  embp[o1] = a1; }
  }
  __syncthreads();
}

// ---------------- embedding kernel: inst-MLP + pos-MLP, normalized sum ------
__global__ __launch_bounds__(TE) void embed_kernel(
    const float* __restrict__ feat_sel, const float* __restrict__ feat_org,
    const float* __restrict__ scale, const float* __restrict__ rand_u,
    const float* __restrict__ iWin, const float* __restrict__ iWhid,
    const float* __restrict__ iWout, const float* __restrict__ pWin,
    const float* __restrict__ pWhid, const float* __restrict__ pWout,
    float* __restrict__ emb, int variant) {
  __shared__ float bufA[BM][LDH];
  __shared__ float bufB[BM][LDH];
  __shared__ float xp[BM][8];
  __shared__ float s_lds[BM];
  __shared__ float invn[BM];

  const int t = threadIdx.x;
  const int p0 = blockIdx.x * BM;
  const int n0 = t, n1 = t + TE;
  float* embp = emb + (size_t)p0 * DIMW;

  if (t < BM) {
    float s = scale[p0 + t];
    if (variant) s = s + fmaxf(0.f, 2.f - s) * rand_u[0];
    s_lds[t] = s;
    bufA[t][384] = s;                    // extra input column for inst net
  }
  for (int idx = t; idx < BM * DIMW; idx += TE) {
    int m = idx / DIMW, k = idx - m * DIMW;
    bufA[m][k] = feat_sel[(size_t)(p0 + m) * DIMW + k];
  }
  __syncthreads();

  // instance net: in(385) -> 5 hidden -> out (no relu)
  layer<true >(bufA, bufB, iWin, 385, n0, n1);
  layer<true >(bufB, bufA, iWhid + (size_t)0 * DIMW * DIMW, DIMW, n0, n1);
  layer<true >(bufA, bufB, iWhid + (size_t)1 * DIMW * DIMW, DIMW, n0, n1);
  layer<true >(bufB, bufA, iWhid + (size_t)2 * DIMW * DIMW, DIMW, n0, n1);
  layer<true >(bufA, bufB, iWhid + (size_t)3 * DIMW * DIMW, DIMW, n0, n1);
  layer<true >(bufB, bufA, iWhid + (size_t)4 * DIMW * DIMW, DIMW, n0, n1);
  layer<false>(bufA, bufB, iWout, DIMW, n0, n1);
  norm_write<false>(bufB, embp, invn, t, n0, n1);

  // position net: in(7) -> 3 hidden -> out
  if (t < BM) {
#pragma unroll
    for (int k = 0; k < 6; ++k) xp[t][k] = feat_org[(size_t)(p0 + t) * 6 + k];
    xp[t][6] = s_lds[t];
  }
  __syncthreads();
  {
    float acc0[BM], acc1[BM];
#pragma unroll
    for (int m = 0; m < BM; ++m) { acc0[m] = 0.f; acc1[m] = 0.f; }
#pragma unroll
    for (int k = 0; k < 7; ++k) {
      float w0 = pWin[(size_t)k * DIMW + n0];
      float w1 = pWin[(size_t)k * DIMW + n1];
#pragma unroll
      for (int m = 0; m < BM; ++m) {
        float h = xp[m][k];
        acc0[m] = fmaf(h, w0, acc0[m]);
        acc1[m] = fmaf(h, w1, acc1[m]);
      }
    }
#pragma unroll
    for (int m = 0; m < BM; ++m) {
      bufA[m][n0] = fmaxf(acc0[m], 0.f);
      bufA[m][n1] = fmaxf(acc1[m], 0.f);
    }
    __syncthreads();
  }
  layer<true >(bufA, bufB, pWhid + (size_t)0 * DIMW * DIMW, DIMW, n0, n1);
  layer<true >(bufB, bufA, pWhid + (size_t)1 * DIMW * DIMW, DIMW, n0, n1);
  layer<true >(bufA, bufB, pWhid + (size_t)2 * DIMW * DIMW, DIMW, n0, n1);
  layer<false>(bufB, bufA, pWout, DIMW, n0, n1);
  norm_write<true>(bufA, embp, invn, t, n0, n1);
}

// ---------------- per-chunk pairwise distances + masked partial sums --------
__global__ __launch_bounds__(256) void dist_kernel(
    const float* __restrict__ emb, const int* __restrict__ mask_id,
    float* __restrict__ part) {
  __shared__ float zt[DBLK][8];
  __shared__ int lab[SCH];
  __shared__ float scratch[4];

  const int c = blockIdx.x, r = blockIdx.y;
  const int t = threadIdx.x;             // column j within chunk
  const int jg = c * SCH + t;
  lab[t] = mask_id[jg];
  const float* zj = emb + (size_t)jg * DIMW;
  const int ibase = r * DBLK;
  const float* zi0 = emb + (size_t)(c * SCH + ibase) * DIMW;

  float d2[DBLK];
#pragma unroll
  for (int i = 0; i < DBLK; ++i) d2[i] = 0.f;

  const int srow = t >> 3, scol = t & 7;

  for (int d0 = 0; d0 < DIMW; d0 += 8) {
    __syncthreads();
    zt[srow][scol] = zi0[(size_t)srow * DIMW + d0 + scol];
    float4 a = *(const float4*)&zj[d0];
    float4 b = *(const float4*)&zj[d0 + 4];
    __syncthreads();
#pragma unroll
    for (int i = 0; i < DBLK; ++i) {
      float4 x = *(const float4*)&zt[i][0];
      float4 y = *(const float4*)&zt[i][4];
      float s = d2[i], df;
      df = x.x - a.x; s = fmaf(df, df, s);
      df = x.y - a.y; s = fmaf(df, df, s);
      df = x.z - a.z; s = fmaf(df, df, s);
      df = x.w - a.w; s = fmaf(df, df, s);
      df = y.x - b.x; s = fmaf(df, df, s);
      df = y.y - b.y; s = fmaf(df, df, s);
      df = y.z - b.z; s = fmaf(df, df, s);
      df = y.w - b.w; s = fmaf(df, df, s);
      d2[i] = s;
    }
  }

  const int labj = lab[t];
  const bool vj = (labj != -1);
  float s_pos = 0.f, s_neg = 0.f, c_pos = 0.f, c_neg = 0.f, c_blk = 0.f;
#pragma unroll
  for (int i = 0; i < DBLK; ++i) {
    int ig = ibase + i;
    int li = lab[ig];
    if ((li != -1) && vj && ig <= t) {   // triu(k=0) & valid_pair
      c_blk += 1.f;
      if (ig < t) {                      // diag excluded from pos & neg
        float d = sqrtf(fmaxf(d2[i], 1e-12f));
        if (li == labj) { s_pos += d; c_pos += 1.f; }
        else            { s_neg += fmaxf(1.f - d, 0.f); c_neg += 1.f; }
      }
    }
  }
  float r0 = block_sum_256(s_pos, scratch, t);
  float r1 = block_sum_256(s_neg, scratch, t);
  float r2 = block_sum_256(c_pos, scratch, t);
  float r3 = block_sum_256(c_neg, scratch, t);
  float r4 = block_sum_256(c_blk, scratch, t);
  if (t == 0) {
    float* pb = part + (size_t)(c * (SCH / DBLK) + r) * 8;
    pb[0] = r0; pb[1] = r1; pb[2] = r2; pb[3] = r3; pb[4] = r4;
  }
}

// ---------------- combine partials into the scalar loss ---------------------
__global__ __launch_bounds__(256) void final_kernel(
    const float* __restrict__ part1, const float* __restrict__ part2,
    float* __restrict__ out) {
  __shared__ float scratch[4];
  const int t = threadIdx.x;             // 256 dist blocks
  const float* p1 = part1 + (size_t)t * 8;
  float sp1 = p1[0], sn = p1[1], cp = p1[2], cn = p1[3], cb = p1[4];
  float sp2 = part2[(size_t)t * 8];
  sp1 = block_sum_256(sp1, scratch, t);
  sn  = block_sum_256(sn,  scratch, t);
  cp  = block_sum_256(cp,  scratch, t);
  cn  = block_sum_256(cn,  scratch, t);
  cb  = block_sum_256(cb,  scratch, t);
  sp2 = block_sum_256(sp2, scratch, t);
  if (t == 0) {
    float loss1 = sp1 / fmaxf(cp, 1.f);
    float loss2 = sp2 / fmaxf(cp, 1.f);
    float loss3 = sn  / fmaxf(cn, 1.f);
    float w_pos = cp / cb;
    float w_neg = cn / cb;
    out[0] = (loss1 + loss2) * w_pos + loss3 * w_neg;
  }
}

extern "C" void kernel_launch(void* const* d_in, const int* in_sizes, int n_in,
                              void* d_out, int out_size, void* d_ws, size_t ws_size,
                              hipStream_t stream) {
  const float* feat_sel = (const float*)d_in[0];
  const float* feat_org = (const float*)d_in[1];
  const float* scale    = (const float*)d_in[2];
  const int*   mask_id  = (const int*)d_in[3];
  const float* rand_u   = (const float*)d_in[4];
  // d_in[5] = chunk_size (python scalar; fixed at 256)
  const float* iWin  = (const float*)d_in[6];
  const float* iWhid = (const float*)d_in[7];
  const float* iWout = (const float*)d_in[8];
  const float* pWin  = (const float*)d_in[9];
  const float* pWhid = (const float*)d_in[10];
  const float* pWout = (const float*)d_in[11];

  float* emb   = (float*)d_ws;                      // 8192*384 floats
  float* part1 = emb + (size_t)NPTS * DIMW;         // 256*8 floats
  float* part2 = part1 + 256 * 8;                   // 256*8 floats

  dim3 gD(NCH, SCH / DBLK);

  embed_kernel<<<NPTS / BM, TE, 0, stream>>>(feat_sel, feat_org, scale, rand_u,
      iWin, iWhid, iWout, pWin, pWhid, pWout, emb, 0);
  dist_kernel<<<gD, 256, 0, stream>>>(emb, mask_id, part1);
  embed_kernel<<<NPTS / BM, TE, 0, stream>>>(feat_sel, feat_org, scale, rand_u,
      iWin, iWhid, iWout, pWin, pWhid, pWout, emb, 1);
  dist_kernel<<<gD, 256, 0, stream>>>(emb, mask_id, part2);
  final_kernel<<<1, 256, 0, stream>>>(part1, part2, (float*)d_out);
}

// Round 2
// 328.705 us; speedup vs baseline: 4.2468x; 4.2468x over previous
//
#include <hip/hip_runtime.h>
#include <math.h>

#define NPTS 8192
#define DIMW 384
#define MB   64          // rows (points) per embed block
#define LDH  424         // LDS k-stride in elements (bank-uniform for b128/b64)
#define KIN  416         // padded input K for inst net (385 -> 416)
#define KPOS 32          // padded input K for pos net (7 -> 32)
#define SCH  256
#define NCH  32
#define DBLK 32

typedef __attribute__((ext_vector_type(8))) short bf16x8;
typedef __attribute__((ext_vector_type(4))) float f32x4;
typedef __attribute__((ext_vector_type(4))) unsigned short us4;

// ---- bf16 weight layout in ws (ushort offsets), all transposed to [n][k] ----
#define SZ_HID   (384*384)
#define OFF_IIN  0
#define SZ_IIN   (384*416)
#define OFF_IHID (OFF_IIN + SZ_IIN)
#define OFF_IOUT (OFF_IHID + 5*SZ_HID)
#define OFF_PIN  (OFF_IOUT + SZ_HID)
#define SZ_PIN   (384*32)
#define OFF_PHID (OFF_PIN + SZ_PIN)
#define OFF_POUT (OFF_PHID + 3*SZ_HID)
#define WTS_USHORTS (OFF_POUT + SZ_HID)          // 1,646,592
#define WTS_BYTES   ((size_t)WTS_USHORTS * 2)    // 3,293,184 (256-aligned)
#define EMB_FLOATS  ((size_t)NPTS * DIMW)
#define EMB_BYTES   (EMB_FLOATS * 4)

__device__ __forceinline__ ushort f2bf(float x) {
  union { float f; unsigned u; } v; v.f = x;
  unsigned r = v.u + 0x7FFF + ((v.u >> 16) & 1);   // RNE
  return (ushort)(r >> 16);
}

// ---------------- weight convert + transpose: dst[n*ldk+k] = bf16(src[k*N+n])
__global__ __launch_bounds__(256) void convert_wts(
    const float* __restrict__ iWin, const float* __restrict__ iWhid,
    const float* __restrict__ iWout, const float* __restrict__ pWin,
    const float* __restrict__ pWhid, const float* __restrict__ pWout,
    ushort* __restrict__ wts) {
  const int seg = blockIdx.y;
  const float* src; ushort* dst; int K, ldk;
  if (seg == 0)      { src = iWin;                      dst = wts + OFF_IIN;                  K = 385; ldk = KIN; }
  else if (seg <= 5) { src = iWhid + (size_t)(seg-1)*SZ_HID; dst = wts + OFF_IHID + (size_t)(seg-1)*SZ_HID; K = 384; ldk = 384; }
  else if (seg == 6) { src = iWout;                     dst = wts + OFF_IOUT;                 K = 384; ldk = 384; }
  else if (seg == 7) { src = pWin;                      dst = wts + OFF_PIN;                  K = 7;   ldk = KPOS; }
  else if (seg <= 10){ src = pWhid + (size_t)(seg-8)*SZ_HID; dst = wts + OFF_PHID + (size_t)(seg-8)*SZ_HID; K = 384; ldk = 384; }
  else               { src = pWout;                     dst = wts + OFF_POUT;                 K = 384; ldk = 384; }
  const int i = blockIdx.x * 256 + threadIdx.x;
  if (i >= K * 384) return;
  const int k = i / 384, n = i - k * 384;
  dst[(size_t)n * ldk + k] = f2bf(src[i]);
}

// ---------------- one MFMA layer: O^T = Wt(A) x H(B); store relu(O) as bf16 --
// wave owns n-rows [n0, n0+48); block owns m-rows [0,64). KW: k-extent.
template <int KW, bool STORE>
__device__ __forceinline__ void mlayer(const ushort* __restrict__ Wt,
    const ushort* __restrict__ bin, ushort* __restrict__ bout,
    int lr, int lq, int n0, f32x4 acc[3][4]) {
#pragma unroll
  for (int i = 0; i < 3; ++i)
#pragma unroll
    for (int j = 0; j < 4; ++j) acc[i][j] = (f32x4)(0.f);
  const int NK = KW / 32;
  for (int ks = 0; ks < NK; ++ks) {
    bf16x8 w[3], h[4];
#pragma unroll
    for (int i = 0; i < 3; ++i)
      w[i] = *(const bf16x8*)&Wt[(size_t)(n0 + i*16 + lr) * KW + ks*32 + lq*8];
#pragma unroll
    for (int j = 0; j < 4; ++j)
      h[j] = *(const bf16x8*)&bin[(j*16 + lr) * LDH + ks*32 + lq*8];
#pragma unroll
    for (int j = 0; j < 4; ++j)
#pragma unroll
      for (int i = 0; i < 3; ++i)
        acc[i][j] = __builtin_amdgcn_mfma_f32_16x16x32_bf16(w[i], h[j], acc[i][j], 0, 0, 0);
  }
  if (STORE) {
#pragma unroll
    for (int i = 0; i < 3; ++i)
#pragma unroll
      for (int j = 0; j < 4; ++j) {
        f32x4 a = acc[i][j];
        us4 o;
        o[0] = f2bf(fmaxf(a[0], 0.f));
        o[1] = f2bf(fmaxf(a[1], 0.f));
        o[2] = f2bf(fmaxf(a[2], 0.f));
        o[3] = f2bf(fmaxf(a[3], 0.f));
        *(us4*)&bout[(j*16 + lr) * LDH + n0 + i*16 + lq*4] = o;
      }
    __syncthreads();
  }
}

// ---------------- L2-normalize rows from accumulators, write/add to emb -----
__device__ __forceinline__ void norm_store(f32x4 acc[3][4], float* __restrict__ embp,
    bool add, int lr, int lq, int wave, int n0, float (*wsum)[64], float* invn) {
#pragma unroll
  for (int j = 0; j < 4; ++j) {
    float s = 0.f;
#pragma unroll
    for (int i = 0; i < 3; ++i) {
      f32x4 a = acc[i][j];
      s = fmaf(a[0], a[0], s); s = fmaf(a[1], a[1], s);
      s = fmaf(a[2], a[2], s); s = fmaf(a[3], a[3], s);
    }
    s += __shfl_xor(s, 16, 64);
    s += __shfl_xor(s, 32, 64);
    if (lq == 0) wsum[wave][j*16 + lr] = s;
  }
  __syncthreads();
  if (threadIdx.x < 64) {
    float tot = 0.f;
#pragma unroll
    for (int w = 0; w < 8; ++w) tot += wsum[w][threadIdx.x];
    invn[threadIdx.x] = 1.f / (sqrtf(tot) + 1e-5f);
  }
  __syncthreads();
#pragma unroll
  for (int j = 0; j < 4; ++j) {
    const float inv = invn[j*16 + lr];
#pragma unroll
    for (int i = 0; i < 3; ++i) {
      float* p = embp + (size_t)(j*16 + lr) * DIMW + n0 + i*16 + lq*4;
      float4 o;
      o.x = acc[i][j][0] * inv; o.y = acc[i][j][1] * inv;
      o.z = acc[i][j][2] * inv; o.w = acc[i][j][3] * inv;
      if (add) { float4 old = *(const float4*)p;
                 o.x += old.x; o.y += old.y; o.z += old.z; o.w += old.w; }
      *(float4*)p = o;
    }
  }
  __syncthreads();   // wsum/invn safe for reuse
}

// ---------------- fused embedding kernel (inst MLP + pos MLP, both variants) -
__global__ __launch_bounds__(512) void embed_mfma(
    const float* __restrict__ feat_sel, const float* __restrict__ feat_org,
    const float* __restrict__ scale, const float* __restrict__ rand_u,
    const ushort* __restrict__ wts, float* __restrict__ emb,
    long long emb_stride, int var_base) {
  __shared__ ushort bufA[MB * LDH];
  __shared__ ushort bufB[MB * LDH];
  __shared__ float s_lds[MB];
  __shared__ float wsum[8][64];
  __shared__ float invn[64];

  const int t = threadIdx.x;
  const int p0 = blockIdx.x * MB;
  const int var = var_base + blockIdx.y;
  float* embp = emb + (long long)blockIdx.y * emb_stride + (size_t)p0 * DIMW;

  if (t < MB) {
    float s = scale[p0 + t];
    if (var) s += fmaxf(0.f, 2.f - s) * rand_u[0];
    s_lds[t] = s;
  }
  // stage inst input: 64 x 384 floats -> bf16 LDS, plus scale col + zero pad
#pragma unroll
  for (int it = 0; it < 12; ++it) {
    int idx = t + it * 512;
    int m = idx / 96, kq = idx - m * 96;
    const float4 v = *(const float4*)&feat_sel[(size_t)(p0 + m) * DIMW + kq * 4];
    us4 o; o[0] = f2bf(v.x); o[1] = f2bf(v.y); o[2] = f2bf(v.z); o[3] = f2bf(v.w);
    *(us4*)&bufA[m * LDH + kq * 4] = o;
  }
  if (t < MB) {
    bufA[t * LDH + 384] = f2bf(s_lds[t]);
#pragma unroll
    for (int k = 385; k < KIN; ++k) bufA[t * LDH + k] = 0;
  }
  __syncthreads();

  const int lane = t & 63, wave = t >> 6;
  const int lr = lane & 15, lq = lane >> 4;
  const int n0 = wave * 48;
  f32x4 acc[3][4];

  // instance net: in(385->416) + 5 hidden + out
  mlayer<KIN,  true >(wts + OFF_IIN,              bufA, bufB, lr, lq, n0, acc);
  mlayer<DIMW, true >(wts + OFF_IHID + 0*SZ_HID,  bufB, bufA, lr, lq, n0, acc);
  mlayer<DIMW, true >(wts + OFF_IHID + 1*SZ_HID,  bufA, bufB, lr, lq, n0, acc);
  mlayer<DIMW, true >(wts + OFF_IHID + 2*SZ_HID,  bufB, bufA, lr, lq, n0, acc);
  mlayer<DIMW, true >(wts + OFF_IHID + 3*SZ_HID,  bufA, bufB, lr, lq, n0, acc);
  mlayer<DIMW, true >(wts + OFF_IHID + 4*SZ_HID,  bufB, bufA, lr, lq, n0, acc);
  mlayer<DIMW, false>(wts + OFF_IOUT,             bufA, bufB, lr, lq, n0, acc);
  norm_store(acc, embp, false, lr, lq, wave, n0, wsum, invn);

  // pos net input: 6 feats + scale, zero-padded to 32
  if (t < MB) {
    const float* fo = feat_org + (size_t)(p0 + t) * 6;
    ushort* r = bufA + t * LDH;
#pragma unroll
    for (int k = 0; k < 6; ++k) r[k] = f2bf(fo[k]);
    r[6] = f2bf(s_lds[t]);
#pragma unroll
    for (int k = 7; k < KPOS; ++k) r[k] = 0;
  }
  __syncthreads();

  // pos net: in(7->32) + 3 hidden + out
  mlayer<KPOS, true >(wts + OFF_PIN,              bufA, bufB, lr, lq, n0, acc);
  mlayer<DIMW, true >(wts + OFF_PHID + 0*SZ_HID,  bufB, bufA, lr, lq, n0, acc);
  mlayer<DIMW, true >(wts + OFF_PHID + 1*SZ_HID,  bufA, bufB, lr, lq, n0, acc);
  mlayer<DIMW, true >(wts + OFF_PHID + 2*SZ_HID,  bufB, bufA, lr, lq, n0, acc);
  mlayer<DIMW, false>(wts + OFF_POUT,             bufA, bufB, lr, lq, n0, acc);
  norm_store(acc, embp, true, lr, lq, wave, n0, wsum, invn);
}

// ---------------- block-wide deterministic sum (256 threads) ----------------
__device__ __forceinline__ float block_sum_256(float v, float* scratch, int t) {
#pragma unroll
  for (int o = 32; o > 0; o >>= 1) v += __shfl_xor(v, o, 64);
  __syncthreads();
  if ((t & 63) == 0) scratch[t >> 6] = v;
  __syncthreads();
  return scratch[0] + scratch[1] + scratch[2] + scratch[3];
}

// ---------------- per-chunk pairwise distances + masked partial sums --------
__global__ __launch_bounds__(256) void dist_kernel(
    const float* __restrict__ emb, const int* __restrict__ mask_id,
    float* __restrict__ part) {
  __shared__ float zt[DBLK][8];
  __shared__ int lab[SCH];
  __shared__ float scratch[4];

  const int c = blockIdx.x, r = blockIdx.y;
  const int t = threadIdx.x;
  const int jg = c * SCH + t;
  lab[t] = mask_id[jg];
  const float* zj = emb + (size_t)jg * DIMW;
  const int ibase = r * DBLK;
  const float* zi0 = emb + (size_t)(c * SCH + ibase) * DIMW;

  float d2[DBLK];
#pragma unroll
  for (int i = 0; i < DBLK; ++i) d2[i] = 0.f;

  const int srow = t >> 3, scol = t & 7;

  for (int d0 = 0; d0 < DIMW; d0 += 8) {
    __syncthreads();
    zt[srow][scol] = zi0[(size_t)srow * DIMW + d0 + scol];
    float4 a = *(const float4*)&zj[d0];
    float4 b = *(const float4*)&zj[d0 + 4];
    __syncthreads();
#pragma unroll
    for (int i = 0; i < DBLK; ++i) {
      float4 x = *(const float4*)&zt[i][0];
      float4 y = *(const float4*)&zt[i][4];
      float s = d2[i], df;
      df = x.x - a.x; s = fmaf(df, df, s);
      df = x.y - a.y; s = fmaf(df, df, s);
      df = x.z - a.z; s = fmaf(df, df, s);
      df = x.w - a.w; s = fmaf(df, df, s);
      df = y.x - b.x; s = fmaf(df, df, s);
      df = y.y - b.y; s = fmaf(df, df, s);
      df = y.z - b.z; s = fmaf(df, df, s);
      df = y.w - b.w; s = fmaf(df, df, s);
      d2[i] = s;
    }
  }

  const int labj = lab[t];
  const bool vj = (labj != -1);
  float s_pos = 0.f, s_neg = 0.f, c_pos = 0.f, c_neg = 0.f, c_blk = 0.f;
#pragma unroll
  for (int i = 0; i < DBLK; ++i) {
    int ig = ibase + i;
    int li = lab[ig];
    if ((li != -1) && vj && ig <= t) {
      c_blk += 1.f;
      if (ig < t) {
        float d = sqrtf(fmaxf(d2[i], 1e-12f));
        if (li == labj) { s_pos += d; c_pos += 1.f; }
        else            { s_neg += fmaxf(1.f - d, 0.f); c_neg += 1.f; }
      }
    }
  }
  float r0 = block_sum_256(s_pos, scratch, t);
  float r1 = block_sum_256(s_neg, scratch, t);
  float r2 = block_sum_256(c_pos, scratch, t);
  float r3 = block_sum_256(c_neg, scratch, t);
  float r4 = block_sum_256(c_blk, scratch, t);
  if (t == 0) {
    float* pb = part + (size_t)(c * (SCH / DBLK) + r) * 8;
    pb[0] = r0; pb[1] = r1; pb[2] = r2; pb[3] = r3; pb[4] = r4;
  }
}

// ---------------- combine partials into the scalar loss ---------------------
__global__ __launch_bounds__(256) void final_kernel(
    const float* __restrict__ part1, const float* __restrict__ part2,
    float* __restrict__ out) {
  __shared__ float scratch[4];
  const int t = threadIdx.x;
  const float* p1 = part1 + (size_t)t * 8;
  float sp1 = p1[0], sn = p1[1], cp = p1[2], cn = p1[3], cb = p1[4];
  float sp2 = part2[(size_t)t * 8];
  sp1 = block_sum_256(sp1, scratch, t);
  sn  = block_sum_256(sn,  scratch, t);
  cp  = block_sum_256(cp,  scratch, t);
  cn  = block_sum_256(cn,  scratch, t);
  cb  = block_sum_256(cb,  scratch, t);
  sp2 = block_sum_256(sp2, scratch, t);
  if (t == 0) {
    float loss1 = sp1 / fmaxf(cp, 1.f);
    float loss2 = sp2 / fmaxf(cp, 1.f);
    float loss3 = sn  / fmaxf(cn, 1.f);
    float w_pos = cp / cb;
    float w_neg = cn / cb;
    out[0] = (loss1 + loss2) * w_pos + loss3 * w_neg;
  }
}

extern "C" void kernel_launch(void* const* d_in, const int* in_sizes, int n_in,
                              void* d_out, int out_size, void* d_ws, size_t ws_size,
                              hipStream_t stream) {
  const float* feat_sel = (const float*)d_in[0];
  const float* feat_org = (const float*)d_in[1];
  const float* scale    = (const float*)d_in[2];
  const int*   mask_id  = (const int*)d_in[3];
  const float* rand_u   = (const float*)d_in[4];
  const float* iWin  = (const float*)d_in[6];
  const float* iWhid = (const float*)d_in[7];
  const float* iWout = (const float*)d_in[8];
  const float* pWin  = (const float*)d_in[9];
  const float* pWhid = (const float*)d_in[10];
  const float* pWout = (const float*)d_in[11];

  ushort* wts = (ushort*)d_ws;
  const bool single = ws_size >= WTS_BYTES + 2 * EMB_BYTES + 65536;
  float* emb1 = (float*)((char*)d_ws + WTS_BYTES);
  float* emb2 = single ? emb1 + EMB_FLOATS : emb1;
  float* part1 = (float*)((char*)d_ws + WTS_BYTES + (single ? 2 : 1) * EMB_BYTES);
  float* part2 = part1 + 256 * 8;

  // weights -> bf16 transposed [n][k] with zero padding
  hipMemsetAsync(wts, 0, WTS_BYTES, stream);
  dim3 gC((385 * 384 + 255) / 256, 12);
  convert_wts<<<gC, 256, 0, stream>>>(iWin, iWhid, iWout, pWin, pWhid, pWout, wts);

  dim3 gD(NCH, SCH / DBLK);
  if (single) {
    dim3 gE(NPTS / MB, 2);
    embed_mfma<<<gE, 512, 0, stream>>>(feat_sel, feat_org, scale, rand_u,
        wts, emb1, (long long)EMB_FLOATS, 0);
    dist_kernel<<<gD, 256, 0, stream>>>(emb1, mask_id, part1);
    dist_kernel<<<gD, 256, 0, stream>>>(emb2, mask_id, part2);
  } else {
    dim3 gE(NPTS / MB, 1);
    embed_mfma<<<gE, 512, 0, stream>>>(feat_sel, feat_org, scale, rand_u,
        wts, emb1, 0, 0);
    dist_kernel<<<gD, 256, 0, stream>>>(emb1, mask_id, part1);
    embed_mfma<<<gE, 512, 0, stream>>>(feat_sel, feat_org, scale, rand_u,
        wts, emb1, 0, 1);
    dist_kernel<<<gD, 256, 0, stream>>>(emb1, mask_id, part2);
  }
  final_kernel<<<1, 256, 0, stream>>>(part1, part2, (float*)d_out);
}

// Round 4
// 174.378 us; speedup vs baseline: 8.0053x; 1.8850x over previous
//
#include <hip/hip_runtime.h>
#include <math.h>

#define NPTS 8192
#define DIMW 384
#define MB   64          // rows (points) per embed block
#define LDH  424         // embed LDS k-stride (elems); row=848B, frag reads at 8-sweep min
#define KIN  416         // padded input K for inst net (385 -> 416)
#define KPOS 32          // padded input K for pos net (7 -> 32)
#define SCH  256
#define NCH  32
#define LZB  136         // dist LDS k-stride (elems); row=272B, conflict-free frags

typedef __attribute__((ext_vector_type(8))) short bf16x8;
typedef __attribute__((ext_vector_type(4))) float f32x4;
typedef __attribute__((ext_vector_type(4))) unsigned short us4;
typedef __attribute__((ext_vector_type(8))) unsigned short us8;

// ---- bf16 weight layout in ws (ushort offsets), all transposed to [n][k] ----
#define SZ_HID   (384*384)
#define OFF_IIN  0
#define SZ_IIN   (384*416)
#define OFF_IHID (OFF_IIN + SZ_IIN)
#define OFF_IOUT (OFF_IHID + 5*SZ_HID)
#define OFF_PIN  (OFF_IOUT + SZ_HID)
#define SZ_PIN   (384*32)
#define OFF_PHID (OFF_PIN + SZ_PIN)
#define OFF_POUT (OFF_PHID + 3*SZ_HID)
#define WTS_USHORTS (OFF_POUT + SZ_HID)
#define WTS_BYTES   ((size_t)WTS_USHORTS * 2)        // 3,293,184
#define EMB_US      ((size_t)NPTS * DIMW)            // ushorts per variant
#define EMB_BYTES   (EMB_US * 2)                     // 6,291,456

__device__ __forceinline__ ushort f2bf(float x) {
  union { float f; unsigned u; } v; v.f = x;
  unsigned r = v.u + 0x7FFF + ((v.u >> 16) & 1);     // RNE
  return (ushort)(r >> 16);
}
__device__ __forceinline__ float bf2f(ushort u) {
  union { unsigned u; float f; } v; v.u = ((unsigned)u) << 16; return v.f;
}

// ---------------- weight convert+transpose, LDS-tiled (coalesced both sides) -
__global__ __launch_bounds__(256) void convert_wts(
    const float* __restrict__ iWin, const float* __restrict__ iWhid,
    const float* __restrict__ iWout, const float* __restrict__ pWin,
    const float* __restrict__ pWhid, const float* __restrict__ pWout,
    ushort* __restrict__ wts) {
  __shared__ float tile[64][65];
  const int seg = blockIdx.y;
  const float* src; ushort* dst; int K, ldk;
  if (seg == 0)      { src = iWin;  dst = wts + OFF_IIN;  K = 385; ldk = KIN; }
  else if (seg <= 5) { src = iWhid + (size_t)(seg-1)*SZ_HID; dst = wts + OFF_IHID + (size_t)(seg-1)*SZ_HID; K = 384; ldk = 384; }
  else if (seg == 6) { src = iWout; dst = wts + OFF_IOUT; K = 384; ldk = 384; }
  else if (seg == 7) { src = pWin;  dst = wts + OFF_PIN;  K = 7;   ldk = KPOS; }
  else if (seg <= 10){ src = pWhid + (size_t)(seg-8)*SZ_HID; dst = wts + OFF_PHID + (size_t)(seg-8)*SZ_HID; K = 384; ldk = 384; }
  else               { src = pWout; dst = wts + OFF_POUT; K = 384; ldk = 384; }
  const int nkt = (K + 63) >> 6;
  const int kt = blockIdx.x / 6, nt = blockIdx.x - kt * 6;
  if (kt >= nkt) return;
  const int k0 = kt * 64, n0 = nt * 64;
  const int t = threadIdx.x;
  const int c = t & 63, rr = t >> 6;
#pragma unroll
  for (int p = 0; p < 16; ++p) {
    int kl = p * 4 + rr;
    int k = k0 + kl;
    tile[kl][c] = (k < K) ? src[(size_t)k * 384 + n0 + c] : 0.f;
  }
  __syncthreads();
#pragma unroll
  for (int p = 0; p < 16; ++p) {
    int nl = p * 4 + rr;
    int k = k0 + c;
    if (k < K) dst[(size_t)(n0 + nl) * ldk + k] = f2bf(tile[c][nl]);
  }
}

// ---------------- one MFMA layer with depth-2 W / depth-1 H prefetch ---------
template <int KW, bool STORE>
__device__ __forceinline__ void mlayer(const ushort* __restrict__ Wt,
    const ushort* __restrict__ bin, ushort* __restrict__ bout,
    int lr, int lq, int n0, f32x4 acc[3][4]) {
  constexpr int NK = KW / 32;
#pragma unroll
  for (int i = 0; i < 3; ++i)
#pragma unroll
    for (int j = 0; j < 4; ++j) acc[i][j] = (f32x4)(0.f);

  bf16x8 w[3][3], h[2][4];
  const ushort* wp = Wt + (size_t)(n0 + lr) * KW + lq * 8;
  const ushort* hp = bin + lr * LDH + lq * 8;

#pragma unroll
  for (int i = 0; i < 3; ++i) w[0][i] = *(const bf16x8*)(wp + (size_t)i * 16 * KW);
#pragma unroll
  for (int j = 0; j < 4; ++j) h[0][j] = *(const bf16x8*)(hp + j * 16 * LDH);
  if (NK > 1) {
#pragma unroll
    for (int i = 0; i < 3; ++i) w[1][i] = *(const bf16x8*)(wp + (size_t)i * 16 * KW + 32);
  }
#pragma unroll
  for (int ks = 0; ks < NK; ++ks) {
    if (ks + 2 < NK) {
#pragma unroll
      for (int i = 0; i < 3; ++i)
        w[(ks + 2) % 3][i] = *(const bf16x8*)(wp + (size_t)i * 16 * KW + (ks + 2) * 32);
    }
    if (ks + 1 < NK) {
#pragma unroll
      for (int j = 0; j < 4; ++j)
        h[(ks + 1) & 1][j] = *(const bf16x8*)(hp + j * 16 * LDH + (ks + 1) * 32);
    }
#pragma unroll
    for (int j = 0; j < 4; ++j)
#pragma unroll
      for (int i = 0; i < 3; ++i)
        acc[i][j] = __builtin_amdgcn_mfma_f32_16x16x32_bf16(w[ks % 3][i], h[ks & 1][j], acc[i][j], 0, 0, 0);
  }
  if (STORE) {
#pragma unroll
    for (int i = 0; i < 3; ++i)
#pragma unroll
      for (int j = 0; j < 4; ++j) {
        f32x4 a = acc[i][j];
        us4 o;
        o[0] = f2bf(fmaxf(a[0], 0.f));
        o[1] = f2bf(fmaxf(a[1], 0.f));
        o[2] = f2bf(fmaxf(a[2], 0.f));
        o[3] = f2bf(fmaxf(a[3], 0.f));
        *(us4*)&bout[(j * 16 + lr) * LDH + n0 + i * 16 + lq * 4] = o;
      }
    __syncthreads();
  }
}

// ---------------- L2-normalize rows from accumulators, write/add bf16 emb ---
__device__ __forceinline__ void norm_store(f32x4 acc[3][4], ushort* __restrict__ embp,
    bool add, int lr, int lq, int wave, int n0, float (*wsum)[64], float* invn) {
#pragma unroll
  for (int j = 0; j < 4; ++j) {
    float s = 0.f;
#pragma unroll
    for (int i = 0; i < 3; ++i) {
      f32x4 a = acc[i][j];
      s = fmaf(a[0], a[0], s); s = fmaf(a[1], a[1], s);
      s = fmaf(a[2], a[2], s); s = fmaf(a[3], a[3], s);
    }
    s += __shfl_xor(s, 16, 64);
    s += __shfl_xor(s, 32, 64);
    if (lq == 0) wsum[wave][j * 16 + lr] = s;
  }
  __syncthreads();
  if (threadIdx.x < 64) {
    float tot = 0.f;
#pragma unroll
    for (int w = 0; w < 8; ++w) tot += wsum[w][threadIdx.x];
    invn[threadIdx.x] = 1.f / (sqrtf(tot) + 1e-5f);
  }
  __syncthreads();
#pragma unroll
  for (int j = 0; j < 4; ++j) {
    const float inv = invn[j * 16 + lr];
#pragma unroll
    for (int i = 0; i < 3; ++i) {
      ushort* p = embp + (size_t)(j * 16 + lr) * DIMW + n0 + i * 16 + lq * 4;
      float o0 = acc[i][j][0] * inv, o1 = acc[i][j][1] * inv;
      float o2 = acc[i][j][2] * inv, o3 = acc[i][j][3] * inv;
      if (add) {
        us4 old = *(const us4*)p;
        o0 += bf2f(old[0]); o1 += bf2f(old[1]);
        o2 += bf2f(old[2]); o3 += bf2f(old[3]);
      }
      us4 o; o[0] = f2bf(o0); o[1] = f2bf(o1); o[2] = f2bf(o2); o[3] = f2bf(o3);
      *(us4*)p = o;
    }
  }
  __syncthreads();
}

// ---------------- fused embedding kernel (both variants via blockIdx.y) ------
__global__ __launch_bounds__(512) void embed_mfma(
    const float* __restrict__ feat_sel, const float* __restrict__ feat_org,
    const float* __restrict__ scale, const float* __restrict__ rand_u,
    const ushort* __restrict__ wts, ushort* __restrict__ emb) {
  __shared__ ushort bufA[MB * LDH];
  __shared__ ushort bufB[MB * LDH];
  __shared__ float s_lds[MB];
  __shared__ float wsum[8][64];
  __shared__ float invn[64];

  const int t = threadIdx.x;
  const int p0 = blockIdx.x * MB;
  const int var = blockIdx.y;
  ushort* embp = emb + (size_t)var * EMB_US + (size_t)p0 * DIMW;

  if (t < MB) {
    float s = scale[p0 + t];
    if (var) s += fmaxf(0.f, 2.f - s) * rand_u[0];
    s_lds[t] = s;
  }
#pragma unroll
  for (int it = 0; it < 12; ++it) {
    int idx = t + it * 512;
    int m = idx / 96, kq = idx - m * 96;
    const float4 v = *(const float4*)&feat_sel[(size_t)(p0 + m) * DIMW + kq * 4];
    us4 o; o[0] = f2bf(v.x); o[1] = f2bf(v.y); o[2] = f2bf(v.z); o[3] = f2bf(v.w);
    *(us4*)&bufA[m * LDH + kq * 4] = o;
  }
  if (t < MB) {
    bufA[t * LDH + 384] = f2bf(s_lds[t]);
#pragma unroll
    for (int k = 385; k < KIN; ++k) bufA[t * LDH + k] = 0;
  }
  __syncthreads();

  const int lane = t & 63, wave = t >> 6;
  const int lr = lane & 15, lq = lane >> 4;
  const int n0 = wave * 48;
  f32x4 acc[3][4];

  mlayer<KIN,  true >(wts + OFF_IIN,             bufA, bufB, lr, lq, n0, acc);
  mlayer<DIMW, true >(wts + OFF_IHID + 0*SZ_HID, bufB, bufA, lr, lq, n0, acc);
  mlayer<DIMW, true >(wts + OFF_IHID + 1*SZ_HID, bufA, bufB, lr, lq, n0, acc);
  mlayer<DIMW, true >(wts + OFF_IHID + 2*SZ_HID, bufB, bufA, lr, lq, n0, acc);
  mlayer<DIMW, true >(wts + OFF_IHID + 3*SZ_HID, bufA, bufB, lr, lq, n0, acc);
  mlayer<DIMW, true >(wts + OFF_IHID + 4*SZ_HID, bufB, bufA, lr, lq, n0, acc);
  mlayer<DIMW, false>(wts + OFF_IOUT,            bufA, bufB, lr, lq, n0, acc);
  norm_store(acc, embp, false, lr, lq, wave, n0, wsum, invn);

  if (t < MB) {
    const float* fo = feat_org + (size_t)(p0 + t) * 6;
    ushort* r = bufA + t * LDH;
#pragma unroll
    for (int k = 0; k < 6; ++k) r[k] = f2bf(fo[k]);
    r[6] = f2bf(s_lds[t]);
#pragma unroll
    for (int k = 7; k < KPOS; ++k) r[k] = 0;
  }
  __syncthreads();

  mlayer<KPOS, true >(wts + OFF_PIN,             bufA, bufB, lr, lq, n0, acc);
  mlayer<DIMW, true >(wts + OFF_PHID + 0*SZ_HID, bufB, bufA, lr, lq, n0, acc);
  mlayer<DIMW, true >(wts + OFF_PHID + 1*SZ_HID, bufA, bufB, lr, lq, n0, acc);
  mlayer<DIMW, true >(wts + OFF_PHID + 2*SZ_HID, bufB, bufA, lr, lq, n0, acc);
  mlayer<DIMW, false>(wts + OFF_POUT,            bufA, bufB, lr, lq, n0, acc);
  norm_store(acc, embp, true, lr, lq, wave, n0, wsum, invn);
}

// ---------------- MFMA gram dist + masked partial sums ----------------------
// grid (chunk, half, variant); block 512 = 8 waves (2 wa x 4 wb), 64x64 tiles
__global__ __launch_bounds__(512) void dist_mfma(
    const ushort* __restrict__ emb, const int* __restrict__ mask_id,
    float* __restrict__ part) {
  __shared__ ushort zb[SCH * LZB];
  __shared__ float sqv[SCH];
  __shared__ int labv[SCH];
  __shared__ float scratch[8];

  const int c = blockIdx.x, hh = blockIdx.y, v = blockIdx.z;
  const int t = threadIdx.x;
  const ushort* embc = emb + (size_t)v * EMB_US + (size_t)c * SCH * DIMW;

  if (t < SCH) labv[t] = mask_id[c * SCH + t];

  const int lane = t & 63, wave = t >> 6;
  const int lr = lane & 15, lq = lane >> 4;
  const int wa = wave >> 2, wb = wave & 3;

  f32x4 acc[4][4];
#pragma unroll
  for (int i = 0; i < 4; ++i)
#pragma unroll
    for (int j = 0; j < 4; ++j) acc[i][j] = (f32x4)(0.f);

  const int sr = t >> 1, sh = (t & 1) * 64;   // staging: row, k-half (elems)
  float sq = 0.f;

  for (int kc = 0; kc < 3; ++kc) {
    __syncthreads();
    const ushort* zrow = embc + (size_t)sr * DIMW + kc * 128 + sh;
    ushort* zd = zb + sr * LZB + sh;
#pragma unroll
    for (int q = 0; q < 8; ++q) {
      us8 x = *(const us8*)&zrow[q * 8];
      *(us8*)&zd[q * 8] = x;
#pragma unroll
      for (int e = 0; e < 8; ++e) { float f = bf2f(x[e]); sq = fmaf(f, f, sq); }
    }
    __syncthreads();
    const ushort* ap = zb + (hh * 128 + wa * 64 + lr) * LZB + lq * 8;
    const ushort* bp = zb + (wb * 64 + lr) * LZB + lq * 8;
#pragma unroll
    for (int ks = 0; ks < 4; ++ks) {
      bf16x8 af[4], bfr[4];
#pragma unroll
      for (int i = 0; i < 4; ++i) af[i] = *(const bf16x8*)(ap + i * 16 * LZB + ks * 32);
#pragma unroll
      for (int j = 0; j < 4; ++j) bfr[j] = *(const bf16x8*)(bp + j * 16 * LZB + ks * 32);
#pragma unroll
      for (int j = 0; j < 4; ++j)
#pragma unroll
        for (int i = 0; i < 4; ++i)
          acc[i][j] = __builtin_amdgcn_mfma_f32_16x16x32_bf16(af[i], bfr[j], acc[i][j], 0, 0, 0);
    }
  }
  sq += __shfl_xor(sq, 1, 64);
  if (!(t & 1)) sqv[sr] = sq;
  __syncthreads();

  float s_pos = 0.f, s_neg = 0.f, c_pos = 0.f, c_neg = 0.f, c_blk = 0.f;
#pragma unroll
  for (int i = 0; i < 4; ++i) {
    const int ib = hh * 128 + wa * 64 + i * 16 + lq * 4;
#pragma unroll
    for (int j = 0; j < 4; ++j) {
      const int jG = wb * 64 + j * 16 + lr;
      const int lj = labv[jG];
      const float sqj = sqv[jG];
#pragma unroll
      for (int vv = 0; vv < 4; ++vv) {
        const int iG = ib + vv;
        const int li = labv[iG];
        if (li != -1 && lj != -1 && iG <= jG) {
          c_blk += 1.f;
          if (iG < jG) {
            float d2 = sqv[iG] + sqj - 2.f * acc[i][j][vv];
            float d = sqrtf(fmaxf(d2, 1e-12f));
            if (li == lj) { s_pos += d; c_pos += 1.f; }
            else          { s_neg += fmaxf(1.f - d, 0.f); c_neg += 1.f; }
          }
        }
      }
    }
  }
  // deterministic block reduce (512 threads)
  float vals[5] = { s_pos, s_neg, c_pos, c_neg, c_blk };
  float res[5];
#pragma unroll
  for (int r = 0; r < 5; ++r) {
    float x = vals[r];
#pragma unroll
    for (int o = 32; o > 0; o >>= 1) x += __shfl_xor(x, o, 64);
    __syncthreads();
    if ((t & 63) == 0) scratch[t >> 6] = x;
    __syncthreads();
    float s = 0.f;
#pragma unroll
    for (int w = 0; w < 8; ++w) s += scratch[w];
    res[r] = s;
  }
  if (t == 0) {
    float* pb = part + (size_t)((v * 2 + hh) * NCH + c) * 8;
    pb[0] = res[0]; pb[1] = res[1]; pb[2] = res[2]; pb[3] = res[3]; pb[4] = res[4];
  }
}

// ---------------- combine 128 partial slots into the scalar loss ------------
__global__ __launch_bounds__(128) void final_kernel(
    const float* __restrict__ part, float* __restrict__ out) {
  __shared__ float scratch[2];
  const int t = threadIdx.x;
  const float* pb = part + (size_t)t * 8;
  const bool v0 = t < 64;
  float sp1 = v0 ? pb[0] : 0.f;
  float sp2 = v0 ? 0.f : pb[0];
  float sn  = v0 ? pb[1] : 0.f;
  float cp  = v0 ? pb[2] : 0.f;
  float cn  = v0 ? pb[3] : 0.f;
  float cb  = v0 ? pb[4] : 0.f;
  float vals[6] = { sp1, sp2, sn, cp, cn, cb };
  float res[6];
#pragma unroll
  for (int r = 0; r < 6; ++r) {
    float x = vals[r];
#pragma unroll
    for (int o = 32; o > 0; o >>= 1) x += __shfl_xor(x, o, 64);
    __syncthreads();
    if ((t & 63) == 0) scratch[t >> 6] = x;
    __syncthreads();
    res[r] = scratch[0] + scratch[1];
  }
  if (t == 0) {
    float l1 = res[0] / fmaxf(res[3], 1.f);
    float l2 = res[1] / fmaxf(res[3], 1.f);
    float l3 = res[2] / fmaxf(res[4], 1.f);
    out[0] = (l1 + l2) * (res[3] / res[5]) + l3 * (res[4] / res[5]);
  }
}

extern "C" void kernel_launch(void* const* d_in, const int* in_sizes, int n_in,
                              void* d_out, int out_size, void* d_ws, size_t ws_size,
                              hipStream_t stream) {
  const float* feat_sel = (const float*)d_in[0];
  const float* feat_org = (const float*)d_in[1];
  const float* scale    = (const float*)d_in[2];
  const int*   mask_id  = (const int*)d_in[3];
  const float* rand_u   = (const float*)d_in[4];
  const float* iWin  = (const float*)d_in[6];
  const float* iWhid = (const float*)d_in[7];
  const float* iWout = (const float*)d_in[8];
  const float* pWin  = (const float*)d_in[9];
  const float* pWhid = (const float*)d_in[10];
  const float* pWout = (const float*)d_in[11];

  ushort* wts = (ushort*)d_ws;
  ushort* emb = (ushort*)((char*)d_ws + WTS_BYTES);          // 2 variants bf16
  float*  part = (float*)((char*)d_ws + WTS_BYTES + 2 * EMB_BYTES);

  hipMemsetAsync(wts, 0, WTS_BYTES, stream);
  dim3 gC(42, 12);
  convert_wts<<<gC, 256, 0, stream>>>(iWin, iWhid, iWout, pWin, pWhid, pWout, wts);

  dim3 gE(NPTS / MB, 2);
  embed_mfma<<<gE, 512, 0, stream>>>(feat_sel, feat_org, scale, rand_u, wts, emb);

  dim3 gD(NCH, 2, 2);
  dist_mfma<<<gD, 512, 0, stream>>>(emb, mask_id, part);

  final_kernel<<<1, 128, 0, stream>>>(part, (float*)d_out);
}

// Round 5
// 120.171 us; speedup vs baseline: 11.6164x; 1.4511x over previous
//
#include <hip/hip_runtime.h>
#include <math.h>

#define NPTS 8192
#define DIMW 384
#define MB   64          // rows (points) per embed block
#define LDH  424         // embed LDS k-stride (elems); frag b128 reads at 8-sweep min
#define KIN  416         // padded input K for inst net (385 -> 416)
#define KPOS 32          // padded input K for pos net (7 -> 32)
#define SCH  256
#define NCH  32
#define LZB  136         // dist LDS k-stride (elems); conflict-free frags

typedef __attribute__((ext_vector_type(8))) short bf16x8;
typedef __attribute__((ext_vector_type(4))) float f32x4;
typedef __attribute__((ext_vector_type(4))) unsigned short us4;
typedef __attribute__((ext_vector_type(8))) unsigned short us8;

// ---- bf16 weight layout in ws (ushort offsets) -----------------------------
// Each layer stored FRAGMENT-CONTIGUOUS: elem (wave, ks, i, lane, e) at linear
// idx ((((wave*NK + ks)*3 + i)*64 + lane)*8 + e), holding
//   W^T[n][k] with n = wave*48 + i*16 + (lane&15), k = ks*32 + (lane>>4)*8 + e
// so each per-k-step W fragment load is one coalesced contiguous 1KB read.
#define SZ_HID   (384*384)
#define OFF_IIN  0
#define SZ_IIN   (384*416)
#define OFF_IHID (OFF_IIN + SZ_IIN)
#define OFF_IOUT (OFF_IHID + 5*SZ_HID)
#define OFF_PIN  (OFF_IOUT + SZ_HID)
#define SZ_PIN   (384*32)
#define OFF_PHID (OFF_PIN + SZ_PIN)
#define OFF_POUT (OFF_PHID + 3*SZ_HID)
#define WTS_USHORTS (OFF_POUT + SZ_HID)
#define WTS_BYTES   ((size_t)WTS_USHORTS * 2)        // 3,293,184
#define EMB_US      ((size_t)NPTS * DIMW)            // ushorts per variant
#define EMB_BYTES   (EMB_US * 2)                     // 6,291,456

__device__ __forceinline__ ushort f2bf(float x) {
  union { float f; unsigned u; } v; v.f = x;
  unsigned r = v.u + 0x7FFF + ((v.u >> 16) & 1);     // RNE
  return (ushort)(r >> 16);
}
__device__ __forceinline__ float bf2f(ushort u) {
  union { unsigned u; float f; } v; v.u = ((unsigned)u) << 16; return v.f;
}

// ---------------- weight convert into fragment-contiguous swizzle ------------
__global__ __launch_bounds__(256) void convert_wts_swz(
    const float* __restrict__ iWin, const float* __restrict__ iWhid,
    const float* __restrict__ iWout, const float* __restrict__ pWin,
    const float* __restrict__ pWhid, const float* __restrict__ pWout,
    ushort* __restrict__ wts) {
  const int seg = blockIdx.y;
  const float* src; ushort* dst; int Ksrc, NKl;
  if (seg == 0)      { src = iWin;  dst = wts + OFF_IIN;  Ksrc = 385; NKl = 13; }
  else if (seg <= 5) { src = iWhid + (size_t)(seg-1)*SZ_HID; dst = wts + OFF_IHID + (size_t)(seg-1)*SZ_HID; Ksrc = 384; NKl = 12; }
  else if (seg == 6) { src = iWout; dst = wts + OFF_IOUT; Ksrc = 384; NKl = 12; }
  else if (seg == 7) { src = pWin;  dst = wts + OFF_PIN;  Ksrc = 7;   NKl = 1;  }
  else if (seg <= 10){ src = pWhid + (size_t)(seg-8)*SZ_HID; dst = wts + OFF_PHID + (size_t)(seg-8)*SZ_HID; Ksrc = 384; NKl = 12; }
  else               { src = pWout; dst = wts + OFF_POUT; Ksrc = 384; NKl = 12; }
  const int t = blockIdx.x * 256 + threadIdx.x;      // one thread per 8 elems
  if (t >= NKl * 1536) return;                       // 8 waves * NK * 3 * 64
  const int lane = t & 63;
  const int frag = t >> 6;
  const int i = frag % 3;
  const int rest = frag / 3;
  const int ks = rest % NKl;
  const int wave = rest / NKl;
  const int n  = wave * 48 + i * 16 + (lane & 15);
  const int kb = ks * 32 + (lane >> 4) * 8;
  us8 o;
#pragma unroll
  for (int e = 0; e < 8; ++e) {
    const int k = kb + e;
    o[e] = (k < Ksrc) ? f2bf(src[(size_t)k * 384 + n]) : (ushort)0;
  }
  *(us8*)&dst[(size_t)t * 8] = o;
}

// ---------------- one MFMA layer; W streamed coalesced, depth-2 prefetch ----
template <int KW, bool STORE>
__device__ __forceinline__ void mlayer(const ushort* __restrict__ Wt,
    const ushort* __restrict__ bin, ushort* __restrict__ bout,
    int wave, int lane, int lr, int lq, int n0, f32x4 acc[3][4]) {
  constexpr int NK = KW / 32;
#pragma unroll
  for (int i = 0; i < 3; ++i)
#pragma unroll
    for (int j = 0; j < 4; ++j) acc[i][j] = (f32x4)(0.f);

  bf16x8 w[3][3], h[2][4];
  const ushort* wp = Wt + (size_t)wave * NK * 1536 + lane * 8;
  const ushort* hp = bin + lr * LDH + lq * 8;

#pragma unroll
  for (int i = 0; i < 3; ++i) w[0][i] = *(const bf16x8*)(wp + i * 512);
#pragma unroll
  for (int j = 0; j < 4; ++j) h[0][j] = *(const bf16x8*)(hp + j * 16 * LDH);
  if (NK > 1) {
#pragma unroll
    for (int i = 0; i < 3; ++i) w[1][i] = *(const bf16x8*)(wp + 1536 + i * 512);
  }
#pragma unroll
  for (int ks = 0; ks < NK; ++ks) {
    if (ks + 2 < NK) {
#pragma unroll
      for (int i = 0; i < 3; ++i)
        w[(ks + 2) % 3][i] = *(const bf16x8*)(wp + (ks + 2) * 1536 + i * 512);
    }
    if (ks + 1 < NK) {
#pragma unroll
      for (int j = 0; j < 4; ++j)
        h[(ks + 1) & 1][j] = *(const bf16x8*)(hp + j * 16 * LDH + (ks + 1) * 32);
    }
#pragma unroll
    for (int j = 0; j < 4; ++j)
#pragma unroll
      for (int i = 0; i < 3; ++i)
        acc[i][j] = __builtin_amdgcn_mfma_f32_16x16x32_bf16(w[ks % 3][i], h[ks & 1][j], acc[i][j], 0, 0, 0);
  }
  if (STORE) {
#pragma unroll
    for (int i = 0; i < 3; ++i)
#pragma unroll
      for (int j = 0; j < 4; ++j) {
        f32x4 a = acc[i][j];
        us4 o;
        o[0] = f2bf(fmaxf(a[0], 0.f));
        o[1] = f2bf(fmaxf(a[1], 0.f));
        o[2] = f2bf(fmaxf(a[2], 0.f));
        o[3] = f2bf(fmaxf(a[3], 0.f));
        *(us4*)&bout[(j * 16 + lr) * LDH + n0 + i * 16 + lq * 4] = o;
      }
    __syncthreads();
  }
}

// ---------------- L2-normalize rows from accumulators, write/add bf16 emb ---
__device__ __forceinline__ void norm_store(f32x4 acc[3][4], ushort* __restrict__ embp,
    bool add, int lr, int lq, int wave, int n0, float (*wsum)[64], float* invn) {
#pragma unroll
  for (int j = 0; j < 4; ++j) {
    float s = 0.f;
#pragma unroll
    for (int i = 0; i < 3; ++i) {
      f32x4 a = acc[i][j];
      s = fmaf(a[0], a[0], s); s = fmaf(a[1], a[1], s);
      s = fmaf(a[2], a[2], s); s = fmaf(a[3], a[3], s);
    }
    s += __shfl_xor(s, 16, 64);
    s += __shfl_xor(s, 32, 64);
    if (lq == 0) wsum[wave][j * 16 + lr] = s;
  }
  __syncthreads();
  if (threadIdx.x < 64) {
    float tot = 0.f;
#pragma unroll
    for (int w = 0; w < 8; ++w) tot += wsum[w][threadIdx.x];
    invn[threadIdx.x] = 1.f / (sqrtf(tot) + 1e-5f);
  }
  __syncthreads();
#pragma unroll
  for (int j = 0; j < 4; ++j) {
    const float inv = invn[j * 16 + lr];
#pragma unroll
    for (int i = 0; i < 3; ++i) {
      ushort* p = embp + (size_t)(j * 16 + lr) * DIMW + n0 + i * 16 + lq * 4;
      float o0 = acc[i][j][0] * inv, o1 = acc[i][j][1] * inv;
      float o2 = acc[i][j][2] * inv, o3 = acc[i][j][3] * inv;
      if (add) {
        us4 old = *(const us4*)p;
        o0 += bf2f(old[0]); o1 += bf2f(old[1]);
        o2 += bf2f(old[2]); o3 += bf2f(old[3]);
      }
      us4 o; o[0] = f2bf(o0); o[1] = f2bf(o1); o[2] = f2bf(o2); o[3] = f2bf(o3);
      *(us4*)p = o;
    }
  }
  __syncthreads();
}

// ---------------- fused embedding kernel (both variants via blockIdx.y) ------
__global__ __launch_bounds__(512) void embed_mfma(
    const float* __restrict__ feat_sel, const float* __restrict__ feat_org,
    const float* __restrict__ scale, const float* __restrict__ rand_u,
    const ushort* __restrict__ wts, ushort* __restrict__ emb) {
  __shared__ ushort bufA[MB * LDH];
  __shared__ ushort bufB[MB * LDH];
  __shared__ float s_lds[MB];
  __shared__ float wsum[8][64];
  __shared__ float invn[64];

  const int t = threadIdx.x;
  const int p0 = blockIdx.x * MB;
  const int var = blockIdx.y;
  ushort* embp = emb + (size_t)var * EMB_US + (size_t)p0 * DIMW;

  if (t < MB) {
    float s = scale[p0 + t];
    if (var) s += fmaxf(0.f, 2.f - s) * rand_u[0];
    s_lds[t] = s;
  }
#pragma unroll
  for (int it = 0; it < 12; ++it) {
    int idx = t + it * 512;
    int m = idx / 96, kq = idx - m * 96;
    const float4 v = *(const float4*)&feat_sel[(size_t)(p0 + m) * DIMW + kq * 4];
    us4 o; o[0] = f2bf(v.x); o[1] = f2bf(v.y); o[2] = f2bf(v.z); o[3] = f2bf(v.w);
    *(us4*)&bufA[m * LDH + kq * 4] = o;
  }
  if (t < MB) {
    bufA[t * LDH + 384] = f2bf(s_lds[t]);
#pragma unroll
    for (int k = 385; k < KIN; ++k) bufA[t * LDH + k] = 0;
  }
  __syncthreads();

  const int lane = t & 63, wave = t >> 6;
  const int lr = lane & 15, lq = lane >> 4;
  const int n0 = wave * 48;
  f32x4 acc[3][4];

  mlayer<KIN,  true >(wts + OFF_IIN,             bufA, bufB, wave, lane, lr, lq, n0, acc);
  mlayer<DIMW, true >(wts + OFF_IHID + 0*SZ_HID, bufB, bufA, wave, lane, lr, lq, n0, acc);
  mlayer<DIMW, true >(wts + OFF_IHID + 1*SZ_HID, bufA, bufB, wave, lane, lr, lq, n0, acc);
  mlayer<DIMW, true >(wts + OFF_IHID + 2*SZ_HID, bufB, bufA, wave, lane, lr, lq, n0, acc);
  mlayer<DIMW, true >(wts + OFF_IHID + 3*SZ_HID, bufA, bufB, wave, lane, lr, lq, n0, acc);
  mlayer<DIMW, true >(wts + OFF_IHID + 4*SZ_HID, bufB, bufA, wave, lane, lr, lq, n0, acc);
  mlayer<DIMW, false>(wts + OFF_IOUT,            bufA, bufB, wave, lane, lr, lq, n0, acc);
  norm_store(acc, embp, false, lr, lq, wave, n0, wsum, invn);

  if (t < MB) {
    const float* fo = feat_org + (size_t)(p0 + t) * 6;
    ushort* r = bufA + t * LDH;
#pragma unroll
    for (int k = 0; k < 6; ++k) r[k] = f2bf(fo[k]);
    r[6] = f2bf(s_lds[t]);
#pragma unroll
    for (int k = 7; k < KPOS; ++k) r[k] = 0;
  }
  __syncthreads();

  mlayer<KPOS, true >(wts + OFF_PIN,             bufA, bufB, wave, lane, lr, lq, n0, acc);
  mlayer<DIMW, true >(wts + OFF_PHID + 0*SZ_HID, bufB, bufA, wave, lane, lr, lq, n0, acc);
  mlayer<DIMW, true >(wts + OFF_PHID + 1*SZ_HID, bufA, bufB, wave, lane, lr, lq, n0, acc);
  mlayer<DIMW, true >(wts + OFF_PHID + 2*SZ_HID, bufB, bufA, wave, lane, lr, lq, n0, acc);
  mlayer<DIMW, false>(wts + OFF_POUT,            bufA, bufB, wave, lane, lr, lq, n0, acc);
  norm_store(acc, embp, true, lr, lq, wave, n0, wsum, invn);
}

// ---------------- MFMA gram dist + masked partial sums ----------------------
// grid (chunk, half, variant); block 512 = 8 waves (2 wa x 4 wb), 64x64 tiles
__global__ __launch_bounds__(512) void dist_mfma(
    const ushort* __restrict__ emb, const int* __restrict__ mask_id,
    float* __restrict__ part) {
  __shared__ ushort zb[SCH * LZB];
  __shared__ float sqv[SCH];
  __shared__ int labv[SCH];
  __shared__ float scratch[8];

  const int c = blockIdx.x, hh = blockIdx.y, v = blockIdx.z;
  const int t = threadIdx.x;
  const ushort* embc = emb + (size_t)v * EMB_US + (size_t)c * SCH * DIMW;

  if (t < SCH) labv[t] = mask_id[c * SCH + t];

  const int lane = t & 63, wave = t >> 6;
  const int lr = lane & 15, lq = lane >> 4;
  const int wa = wave >> 2, wb = wave & 3;

  f32x4 acc[4][4];
#pragma unroll
  for (int i = 0; i < 4; ++i)
#pragma unroll
    for (int j = 0; j < 4; ++j) acc[i][j] = (f32x4)(0.f);

  const int sr = t >> 1, sh = (t & 1) * 64;   // staging: row, k-half (elems)
  float sq = 0.f;

  for (int kc = 0; kc < 3; ++kc) {
    __syncthreads();
    const ushort* zrow = embc + (size_t)sr * DIMW + kc * 128 + sh;
    ushort* zd = zb + sr * LZB + sh;
#pragma unroll
    for (int q = 0; q < 8; ++q) {
      us8 x = *(const us8*)&zrow[q * 8];
      *(us8*)&zd[q * 8] = x;
#pragma unroll
      for (int e = 0; e < 8; ++e) { float f = bf2f(x[e]); sq = fmaf(f, f, sq); }
    }
    __syncthreads();
    const ushort* ap = zb + (hh * 128 + wa * 64 + lr) * LZB + lq * 8;
    const ushort* bp = zb + (wb * 64 + lr) * LZB + lq * 8;
#pragma unroll
    for (int ks = 0; ks < 4; ++ks) {
      bf16x8 af[4], bfr[4];
#pragma unroll
      for (int i = 0; i < 4; ++i) af[i] = *(const bf16x8*)(ap + i * 16 * LZB + ks * 32);
#pragma unroll
      for (int j = 0; j < 4; ++j) bfr[j] = *(const bf16x8*)(bp + j * 16 * LZB + ks * 32);
#pragma unroll
      for (int j = 0; j < 4; ++j)
#pragma unroll
        for (int i = 0; i < 4; ++i)
          acc[i][j] = __builtin_amdgcn_mfma_f32_16x16x32_bf16(af[i], bfr[j], acc[i][j], 0, 0, 0);
    }
  }
  sq += __shfl_xor(sq, 1, 64);
  if (!(t & 1)) sqv[sr] = sq;
  __syncthreads();

  float s_pos = 0.f, s_neg = 0.f, c_pos = 0.f, c_neg = 0.f, c_blk = 0.f;
#pragma unroll
  for (int i = 0; i < 4; ++i) {
    const int ib = hh * 128 + wa * 64 + i * 16 + lq * 4;
#pragma unroll
    for (int j = 0; j < 4; ++j) {
      const int jG = wb * 64 + j * 16 + lr;
      const int lj = labv[jG];
      const float sqj = sqv[jG];
#pragma unroll
      for (int vv = 0; vv < 4; ++vv) {
        const int iG = ib + vv;
        const int li = labv[iG];
        if (li != -1 && lj != -1 && iG <= jG) {
          c_blk += 1.f;
          if (iG < jG) {
            float d2 = sqv[iG] + sqj - 2.f * acc[i][j][vv];
            float d = sqrtf(fmaxf(d2, 1e-12f));
            if (li == lj) { s_pos += d; c_pos += 1.f; }
            else          { s_neg += fmaxf(1.f - d, 0.f); c_neg += 1.f; }
          }
        }
      }
    }
  }
  // deterministic block reduce (512 threads)
  float vals[5] = { s_pos, s_neg, c_pos, c_neg, c_blk };
  float res[5];
#pragma unroll
  for (int r = 0; r < 5; ++r) {
    float x = vals[r];
#pragma unroll
    for (int o = 32; o > 0; o >>= 1) x += __shfl_xor(x, o, 64);
    __syncthreads();
    if ((t & 63) == 0) scratch[t >> 6] = x;
    __syncthreads();
    float s = 0.f;
#pragma unroll
    for (int w = 0; w < 8; ++w) s += scratch[w];
    res[r] = s;
  }
  if (t == 0) {
    float* pb = part + (size_t)((v * 2 + hh) * NCH + c) * 8;
    pb[0] = res[0]; pb[1] = res[1]; pb[2] = res[2]; pb[3] = res[3]; pb[4] = res[4];
  }
}

// ---------------- combine 128 partial slots into the scalar loss ------------
__global__ __launch_bounds__(128) void final_kernel(
    const float* __restrict__ part, float* __restrict__ out) {
  __shared__ float scratch[2];
  const int t = threadIdx.x;
  const float* pb = part + (size_t)t * 8;
  const bool v0 = t < 64;
  float sp1 = v0 ? pb[0] : 0.f;
  float sp2 = v0 ? 0.f : pb[0];
  float sn  = v0 ? pb[1] : 0.f;
  float cp  = v0 ? pb[2] : 0.f;
  float cn  = v0 ? pb[3] : 0.f;
  float cb  = v0 ? pb[4] : 0.f;
  float vals[6] = { sp1, sp2, sn, cp, cn, cb };
  float res[6];
#pragma unroll
  for (int r = 0; r < 6; ++r) {
    float x = vals[r];
#pragma unroll
    for (int o = 32; o > 0; o >>= 1) x += __shfl_xor(x, o, 64);
    __syncthreads();
    if ((t & 63) == 0) scratch[t >> 6] = x;
    __syncthreads();
    res[r] = scratch[0] + scratch[1];
  }
  if (t == 0) {
    float l1 = res[0] / fmaxf(res[3], 1.f);
    float l2 = res[1] / fmaxf(res[3], 1.f);
    float l3 = res[2] / fmaxf(res[4], 1.f);
    out[0] = (l1 + l2) * (res[3] / res[5]) + l3 * (res[4] / res[5]);
  }
}

extern "C" void kernel_launch(void* const* d_in, const int* in_sizes, int n_in,
                              void* d_out, int out_size, void* d_ws, size_t ws_size,
                              hipStream_t stream) {
  const float* feat_sel = (const float*)d_in[0];
  const float* feat_org = (const float*)d_in[1];
  const float* scale    = (const float*)d_in[2];
  const int*   mask_id  = (const int*)d_in[3];
  const float* rand_u   = (const float*)d_in[4];
  const float* iWin  = (const float*)d_in[6];
  const float* iWhid = (const float*)d_in[7];
  const float* iWout = (const float*)d_in[8];
  const float* pWin  = (const float*)d_in[9];
  const float* pWhid = (const float*)d_in[10];
  const float* pWout = (const float*)d_in[11];

  ushort* wts = (ushort*)d_ws;
  ushort* emb = (ushort*)((char*)d_ws + WTS_BYTES);          // 2 variants bf16
  float*  part = (float*)((char*)d_ws + WTS_BYTES + 2 * EMB_BYTES);

  dim3 gC(78, 12);    // 78*256 threads covers max layer (NK=13 -> 19968)
  convert_wts_swz<<<gC, 256, 0, stream>>>(iWin, iWhid, iWout, pWin, pWhid, pWout, wts);

  dim3 gE(NPTS / MB, 2);
  embed_mfma<<<gE, 512, 0, stream>>>(feat_sel, feat_org, scale, rand_u, wts, emb);

  dim3 gD(NCH, 2, 2);
  dist_mfma<<<gD, 512, 0, stream>>>(emb, mask_id, part);

  final_kernel<<<1, 128, 0, stream>>>(part, (float*)d_out);
}

// Round 6
// 105.458 us; speedup vs baseline: 13.2370x; 1.1395x over previous
//
#include <hip/hip_runtime.h>
#include <math.h>

#define NPTS 8192
#define DIMW 384
#define MB   64          // rows (points) per embed block
#define LDH  424         // embed LDS k-stride (elems); ~2-way banks on frag reads
#define KIN  416         // padded input K for inst net (385 -> 416)
#define KPOS 32          // padded input K for pos net (7 -> 32)
#define SCH  256
#define NCH  32
#define LZB  136         // dist LDS k-stride (elems); conflict-free frags
#define EWAVES 12        // embed waves per block
#define ETHREADS (EWAVES * 64)

typedef __attribute__((ext_vector_type(8))) short bf16x8;
typedef __attribute__((ext_vector_type(4))) float f32x4;
typedef __attribute__((ext_vector_type(4))) unsigned short us4;
typedef __attribute__((ext_vector_type(8))) unsigned short us8;

// ---- bf16 weight layout in ws (ushort offsets) -----------------------------
// FRAGMENT-CONTIGUOUS for 12 waves x 2 i-frags: elem (wave, ks, i, lane, e) at
// linear idx ((((wave*NK + ks)*2 + i)*64 + lane)*8 + e), holding W^T[n][k],
//   n = wave*32 + i*16 + (lane&15), k = ks*32 + (lane>>4)*8 + e
// -> each per-k-step W fragment load is one coalesced contiguous 1KB read.
#define SZ_HID   (384*384)
#define OFF_IIN  0
#define SZ_IIN   (384*416)
#define OFF_IHID (OFF_IIN + SZ_IIN)
#define OFF_IOUT (OFF_IHID + 5*SZ_HID)
#define OFF_PIN  (OFF_IOUT + SZ_HID)
#define SZ_PIN   (384*32)
#define OFF_PHID (OFF_PIN + SZ_PIN)
#define OFF_POUT (OFF_PHID + 3*SZ_HID)
#define WTS_USHORTS (OFF_POUT + SZ_HID)
#define WTS_BYTES   ((size_t)WTS_USHORTS * 2)        // 3,293,184
#define EMB_US      ((size_t)NPTS * DIMW)            // ushorts per variant
#define EMB_BYTES   (EMB_US * 2)                     // 6,291,456

__device__ __forceinline__ ushort f2bf(float x) {
  union { float f; unsigned u; } v; v.f = x;
  unsigned r = v.u + 0x7FFF + ((v.u >> 16) & 1);     // RNE
  return (ushort)(r >> 16);
}
__device__ __forceinline__ float bf2f(ushort u) {
  union { unsigned u; float f; } v; v.u = ((unsigned)u) << 16; return v.f;
}

// ---------------- weight convert into fragment-contiguous swizzle ------------
__global__ __launch_bounds__(256) void convert_wts_swz(
    const float* __restrict__ iWin, const float* __restrict__ iWhid,
    const float* __restrict__ iWout, const float* __restrict__ pWin,
    const float* __restrict__ pWhid, const float* __restrict__ pWout,
    ushort* __restrict__ wts) {
  const int seg = blockIdx.y;
  const float* src; ushort* dst; int Ksrc, NKl;
  if (seg == 0)      { src = iWin;  dst = wts + OFF_IIN;  Ksrc = 385; NKl = 13; }
  else if (seg <= 5) { src = iWhid + (size_t)(seg-1)*SZ_HID; dst = wts + OFF_IHID + (size_t)(seg-1)*SZ_HID; Ksrc = 384; NKl = 12; }
  else if (seg == 6) { src = iWout; dst = wts + OFF_IOUT; Ksrc = 384; NKl = 12; }
  else if (seg == 7) { src = pWin;  dst = wts + OFF_PIN;  Ksrc = 7;   NKl = 1;  }
  else if (seg <= 10){ src = pWhid + (size_t)(seg-8)*SZ_HID; dst = wts + OFF_PHID + (size_t)(seg-8)*SZ_HID; Ksrc = 384; NKl = 12; }
  else               { src = pWout; dst = wts + OFF_POUT; Ksrc = 384; NKl = 12; }
  const int t = blockIdx.x * 256 + threadIdx.x;      // one thread per 8 elems
  if (t >= NKl * 1536) return;                       // 12 waves * NK * 2 * 64
  const int lane = t & 63;
  const int frag = t >> 6;
  const int i = frag & 1;
  const int rest = frag >> 1;
  const int ks = rest % NKl;
  const int wave = rest / NKl;
  const int n  = wave * 32 + i * 16 + (lane & 15);
  const int kb = ks * 32 + (lane >> 4) * 8;
  us8 o;
#pragma unroll
  for (int e = 0; e < 8; ++e) {
    const int k = kb + e;
    o[e] = (k < Ksrc) ? f2bf(src[(size_t)k * 384 + n]) : (ushort)0;
  }
  *(us8*)&dst[(size_t)t * 8] = o;
}

// ---------------- one MFMA layer; coalesced W stream, depth-4 W prefetch ----
template <int KW, bool STORE>
__device__ __forceinline__ void mlayer(const ushort* __restrict__ Wt,
    const ushort* __restrict__ bin, ushort* __restrict__ bout,
    int wave, int lane, int lr, int lq, int n0, f32x4 acc[2][4]) {
  constexpr int NK = KW / 32;
#pragma unroll
  for (int i = 0; i < 2; ++i)
#pragma unroll
    for (int j = 0; j < 4; ++j) acc[i][j] = (f32x4)(0.f);

  bf16x8 w[5][2], h[2][4];
  const ushort* wp = Wt + (size_t)wave * NK * 1024 + lane * 8;
  const ushort* hp = bin + lr * LDH + lq * 8;

#pragma unroll
  for (int d = 0; d < 4; ++d) {
    if (d < NK) {
#pragma unroll
      for (int i = 0; i < 2; ++i)
        w[d][i] = *(const bf16x8*)(wp + d * 1024 + i * 512);
    }
  }
#pragma unroll
  for (int j = 0; j < 4; ++j) h[0][j] = *(const bf16x8*)(hp + j * 16 * LDH);

#pragma unroll
  for (int ks = 0; ks < NK; ++ks) {
    if (ks + 4 < NK) {
#pragma unroll
      for (int i = 0; i < 2; ++i)
        w[(ks + 4) % 5][i] = *(const bf16x8*)(wp + (ks + 4) * 1024 + i * 512);
    }
    if (ks + 1 < NK) {
#pragma unroll
      for (int j = 0; j < 4; ++j)
        h[(ks + 1) & 1][j] = *(const bf16x8*)(hp + j * 16 * LDH + (ks + 1) * 32);
    }
#pragma unroll
    for (int j = 0; j < 4; ++j)
#pragma unroll
      for (int i = 0; i < 2; ++i)
        acc[i][j] = __builtin_amdgcn_mfma_f32_16x16x32_bf16(w[ks % 5][i], h[ks & 1][j], acc[i][j], 0, 0, 0);
  }
  if (STORE) {
#pragma unroll
    for (int i = 0; i < 2; ++i)
#pragma unroll
      for (int j = 0; j < 4; ++j) {
        f32x4 a = acc[i][j];
        us4 o;
        o[0] = f2bf(fmaxf(a[0], 0.f));
        o[1] = f2bf(fmaxf(a[1], 0.f));
        o[2] = f2bf(fmaxf(a[2], 0.f));
        o[3] = f2bf(fmaxf(a[3], 0.f));
        *(us4*)&bout[(j * 16 + lr) * LDH + n0 + i * 16 + lq * 4] = o;
      }
    __syncthreads();
  }
}

// ---------------- L2-normalize rows from accumulators, write/add bf16 emb ---
__device__ __forceinline__ void norm_store(f32x4 acc[2][4], ushort* __restrict__ embp,
    bool add, int lr, int lq, int wave, int n0, float (*wsum)[64], float* invn) {
#pragma unroll
  for (int j = 0; j < 4; ++j) {
    float s = 0.f;
#pragma unroll
    for (int i = 0; i < 2; ++i) {
      f32x4 a = acc[i][j];
      s = fmaf(a[0], a[0], s); s = fmaf(a[1], a[1], s);
      s = fmaf(a[2], a[2], s); s = fmaf(a[3], a[3], s);
    }
    s += __shfl_xor(s, 16, 64);
    s += __shfl_xor(s, 32, 64);
    if (lq == 0) wsum[wave][j * 16 + lr] = s;
  }
  __syncthreads();
  if (threadIdx.x < 64) {
    float tot = 0.f;
#pragma unroll
    for (int w = 0; w < EWAVES; ++w) tot += wsum[w][threadIdx.x];
    invn[threadIdx.x] = 1.f / (sqrtf(tot) + 1e-5f);
  }
  __syncthreads();
#pragma unroll
  for (int j = 0; j < 4; ++j) {
    const float inv = invn[j * 16 + lr];
#pragma unroll
    for (int i = 0; i < 2; ++i) {
      ushort* p = embp + (size_t)(j * 16 + lr) * DIMW + n0 + i * 16 + lq * 4;
      float o0 = acc[i][j][0] * inv, o1 = acc[i][j][1] * inv;
      float o2 = acc[i][j][2] * inv, o3 = acc[i][j][3] * inv;
      if (add) {
        us4 old = *(const us4*)p;
        o0 += bf2f(old[0]); o1 += bf2f(old[1]);
        o2 += bf2f(old[2]); o3 += bf2f(old[3]);
      }
      us4 o; o[0] = f2bf(o0); o[1] = f2bf(o1); o[2] = f2bf(o2); o[3] = f2bf(o3);
      *(us4*)p = o;
    }
  }
  __syncthreads();
}

// ---------------- fused embedding kernel (both variants via blockIdx.y) ------
__global__ __launch_bounds__(ETHREADS) void embed_mfma(
    const float* __restrict__ feat_sel, const float* __restrict__ feat_org,
    const float* __restrict__ scale, const float* __restrict__ rand_u,
    const ushort* __restrict__ wts, ushort* __restrict__ emb) {
  __shared__ ushort bufA[MB * LDH];
  __shared__ ushort bufB[MB * LDH];
  __shared__ float s_lds[MB];
  __shared__ float wsum[EWAVES][64];
  __shared__ float invn[64];

  const int t = threadIdx.x;
  const int p0 = blockIdx.x * MB;
  const int var = blockIdx.y;
  ushort* embp = emb + (size_t)var * EMB_US + (size_t)p0 * DIMW;

  if (t < MB) {
    float s = scale[p0 + t];
    if (var) s += fmaxf(0.f, 2.f - s) * rand_u[0];
    s_lds[t] = s;
  }
#pragma unroll
  for (int it = 0; it < 8; ++it) {
    int idx = t + it * ETHREADS;
    int m = idx / 96, kq = idx - m * 96;
    const float4 v = *(const float4*)&feat_sel[(size_t)(p0 + m) * DIMW + kq * 4];
    us4 o; o[0] = f2bf(v.x); o[1] = f2bf(v.y); o[2] = f2bf(v.z); o[3] = f2bf(v.w);
    *(us4*)&bufA[m * LDH + kq * 4] = o;
  }
  if (t < MB) {
    bufA[t * LDH + 384] = f2bf(s_lds[t]);
#pragma unroll
    for (int k = 385; k < KIN; ++k) bufA[t * LDH + k] = 0;
  }
  __syncthreads();

  const int lane = t & 63, wave = t >> 6;
  const int lr = lane & 15, lq = lane >> 4;
  const int n0 = wave * 32;
  f32x4 acc[2][4];

  mlayer<KIN,  true >(wts + OFF_IIN,             bufA, bufB, wave, lane, lr, lq, n0, acc);
  mlayer<DIMW, true >(wts + OFF_IHID + 0*SZ_HID, bufB, bufA, wave, lane, lr, lq, n0, acc);
  mlayer<DIMW, true >(wts + OFF_IHID + 1*SZ_HID, bufA, bufB, wave, lane, lr, lq, n0, acc);
  mlayer<DIMW, true >(wts + OFF_IHID + 2*SZ_HID, bufB, bufA, wave, lane, lr, lq, n0, acc);
  mlayer<DIMW, true >(wts + OFF_IHID + 3*SZ_HID, bufA, bufB, wave, lane, lr, lq, n0, acc);
  mlayer<DIMW, true >(wts + OFF_IHID + 4*SZ_HID, bufB, bufA, wave, lane, lr, lq, n0, acc);
  mlayer<DIMW, false>(wts + OFF_IOUT,            bufA, bufB, wave, lane, lr, lq, n0, acc);
  norm_store(acc, embp, false, lr, lq, wave, n0, wsum, invn);

  if (t < MB) {
    const float* fo = feat_org + (size_t)(p0 + t) * 6;
    ushort* r = bufA + t * LDH;
#pragma unroll
    for (int k = 0; k < 6; ++k) r[k] = f2bf(fo[k]);
    r[6] = f2bf(s_lds[t]);
#pragma unroll
    for (int k = 7; k < KPOS; ++k) r[k] = 0;
  }
  __syncthreads();

  mlayer<KPOS, true >(wts + OFF_PIN,             bufA, bufB, wave, lane, lr, lq, n0, acc);
  mlayer<DIMW, true >(wts + OFF_PHID + 0*SZ_HID, bufB, bufA, wave, lane, lr, lq, n0, acc);
  mlayer<DIMW, true >(wts + OFF_PHID + 1*SZ_HID, bufA, bufB, wave, lane, lr, lq, n0, acc);
  mlayer<DIMW, true >(wts + OFF_PHID + 2*SZ_HID, bufB, bufA, wave, lane, lr, lq, n0, acc);
  mlayer<DIMW, false>(wts + OFF_POUT,            bufA, bufB, wave, lane, lr, lq, n0, acc);
  norm_store(acc, embp, true, lr, lq, wave, n0, wsum, invn);
}

// ---------------- MFMA gram dist + masked partial sums ----------------------
// grid (chunk, half, variant); block 512 = 8 waves (2 wa x 4 wb), 64x64 tiles
__global__ __launch_bounds__(512) void dist_mfma(
    const ushort* __restrict__ emb, const int* __restrict__ mask_id,
    float* __restrict__ part) {
  __shared__ ushort zb[SCH * LZB];
  __shared__ float sqv[SCH];
  __shared__ int labv[SCH];
  __shared__ float scratch[8];

  const int c = blockIdx.x, hh = blockIdx.y, v = blockIdx.z;
  const int t = threadIdx.x;
  const ushort* embc = emb + (size_t)v * EMB_US + (size_t)c * SCH * DIMW;

  if (t < SCH) labv[t] = mask_id[c * SCH + t];

  const int lane = t & 63, wave = t >> 6;
  const int lr = lane & 15, lq = lane >> 4;
  const int wa = wave >> 2, wb = wave & 3;

  f32x4 acc[4][4];
#pragma unroll
  for (int i = 0; i < 4; ++i)
#pragma unroll
    for (int j = 0; j < 4; ++j) acc[i][j] = (f32x4)(0.f);

  const int sr = t >> 1, sh = (t & 1) * 64;   // staging: row, k-half (elems)
  float sq = 0.f;

  for (int kc = 0; kc < 3; ++kc) {
    __syncthreads();
    const ushort* zrow = embc + (size_t)sr * DIMW + kc * 128 + sh;
    ushort* zd = zb + sr * LZB + sh;
#pragma unroll
    for (int q = 0; q < 8; ++q) {
      us8 x = *(const us8*)&zrow[q * 8];
      *(us8*)&zd[q * 8] = x;
#pragma unroll
      for (int e = 0; e < 8; ++e) { float f = bf2f(x[e]); sq = fmaf(f, f, sq); }
    }
    __syncthreads();
    const ushort* ap = zb + (hh * 128 + wa * 64 + lr) * LZB + lq * 8;
    const ushort* bp = zb + (wb * 64 + lr) * LZB + lq * 8;
#pragma unroll
    for (int ks = 0; ks < 4; ++ks) {
      bf16x8 af[4], bfr[4];
#pragma unroll
      for (int i = 0; i < 4; ++i) af[i] = *(const bf16x8*)(ap + i * 16 * LZB + ks * 32);
#pragma unroll
      for (int j = 0; j < 4; ++j) bfr[j] = *(const bf16x8*)(bp + j * 16 * LZB + ks * 32);
#pragma unroll
      for (int j = 0; j < 4; ++j)
#pragma unroll
        for (int i = 0; i < 4; ++i)
          acc[i][j] = __builtin_amdgcn_mfma_f32_16x16x32_bf16(af[i], bfr[j], acc[i][j], 0, 0, 0);
    }
  }
  sq += __shfl_xor(sq, 1, 64);
  if (!(t & 1)) sqv[sr] = sq;
  __syncthreads();

  float s_pos = 0.f, s_neg = 0.f, c_pos = 0.f, c_neg = 0.f, c_blk = 0.f;
#pragma unroll
  for (int i = 0; i < 4; ++i) {
    const int ib = hh * 128 + wa * 64 + i * 16 + lq * 4;
#pragma unroll
    for (int j = 0; j < 4; ++j) {
      const int jG = wb * 64 + j * 16 + lr;
      const int lj = labv[jG];
      const float sqj = sqv[jG];
#pragma unroll
      for (int vv = 0; vv < 4; ++vv) {
        const int iG = ib + vv;
        const int li = labv[iG];
        if (li != -1 && lj != -1 && iG <= jG) {
          c_blk += 1.f;
          if (iG < jG) {
            float d2 = sqv[iG] + sqj - 2.f * acc[i][j][vv];
            float d = sqrtf(fmaxf(d2, 1e-12f));
            if (li == lj) { s_pos += d; c_pos += 1.f; }
            else          { s_neg += fmaxf(1.f - d, 0.f); c_neg += 1.f; }
          }
        }
      }
    }
  }
  // deterministic block reduce (512 threads)
  float vals[5] = { s_pos, s_neg, c_pos, c_neg, c_blk };
  float res[5];
#pragma unroll
  for (int r = 0; r < 5; ++r) {
    float x = vals[r];
#pragma unroll
    for (int o = 32; o > 0; o >>= 1) x += __shfl_xor(x, o, 64);
    __syncthreads();
    if ((t & 63) == 0) scratch[t >> 6] = x;
    __syncthreads();
    float s = 0.f;
#pragma unroll
    for (int w = 0; w < 8; ++w) s += scratch[w];
    res[r] = s;
  }
  if (t == 0) {
    float* pb = part + (size_t)((v * 2 + hh) * NCH + c) * 8;
    pb[0] = res[0]; pb[1] = res[1]; pb[2] = res[2]; pb[3] = res[3]; pb[4] = res[4];
  }
}

// ---------------- combine 128 partial slots into the scalar loss ------------
__global__ __launch_bounds__(128) void final_kernel(
    const float* __restrict__ part, float* __restrict__ out) {
  __shared__ float scratch[2];
  const int t = threadIdx.x;
  const float* pb = part + (size_t)t * 8;
  const bool v0 = t < 64;
  float sp1 = v0 ? pb[0] : 0.f;
  float sp2 = v0 ? 0.f : pb[0];
  float sn  = v0 ? pb[1] : 0.f;
  float cp  = v0 ? pb[2] : 0.f;
  float cn  = v0 ? pb[3] : 0.f;
  float cb  = v0 ? pb[4] : 0.f;
  float vals[6] = { sp1, sp2, sn, cp, cn, cb };
  float res[6];
#pragma unroll
  for (int r = 0; r < 6; ++r) {
    float x = vals[r];
#pragma unroll
    for (int o = 32; o > 0; o >>= 1) x += __shfl_xor(x, o, 64);
    __syncthreads();
    if ((t & 63) == 0) scratch[t >> 6] = x;
    __syncthreads();
    res[r] = scratch[0] + scratch[1];
  }
  if (t == 0) {
    float l1 = res[0] / fmaxf(res[3], 1.f);
    float l2 = res[1] / fmaxf(res[3], 1.f);
    float l3 = res[2] / fmaxf(res[4], 1.f);
    out[0] = (l1 + l2) * (res[3] / res[5]) + l3 * (res[4] / res[5]);
  }
}

extern "C" void kernel_launch(void* const* d_in, const int* in_sizes, int n_in,
                              void* d_out, int out_size, void* d_ws, size_t ws_size,
                              hipStream_t stream) {
  const float* feat_sel = (const float*)d_in[0];
  const float* feat_org = (const float*)d_in[1];
  const float* scale    = (const float*)d_in[2];
  const int*   mask_id  = (const int*)d_in[3];
  const float* rand_u   = (const float*)d_in[4];
  const float* iWin  = (const float*)d_in[6];
  const float* iWhid = (const float*)d_in[7];
  const float* iWout = (const float*)d_in[8];
  const float* pWin  = (const float*)d_in[9];
  const float* pWhid = (const float*)d_in[10];
  const float* pWout = (const float*)d_in[11];

  ushort* wts = (ushort*)d_ws;
  ushort* emb = (ushort*)((char*)d_ws + WTS_BYTES);          // 2 variants bf16
  float*  part = (float*)((char*)d_ws + WTS_BYTES + 2 * EMB_BYTES);

  dim3 gC(78, 12);    // 78*256 threads covers max layer (NK=13 -> 19968)
  convert_wts_swz<<<gC, 256, 0, stream>>>(iWin, iWhid, iWout, pWin, pWhid, pWout, wts);

  dim3 gE(NPTS / MB, 2);
  embed_mfma<<<gE, ETHREADS, 0, stream>>>(feat_sel, feat_org, scale, rand_u, wts, emb);

  dim3 gD(NCH, 2, 2);
  dist_mfma<<<gD, 512, 0, stream>>>(emb, mask_id, part);

  final_kernel<<<1, 128, 0, stream>>>(part, (float*)d_out);
}